// Round 1
// baseline (658.021 us; speedup 1.0000x reference)
//
#include <hip/hip_runtime.h>

// Problem constants (fixed shapes from reference setup_inputs)
#define N_INST 32768
#define DIM    2048
#define DP     512
#define NCLS   4

typedef _Float16 half4_t __attribute__((ext_vector_type(4)));
typedef _Float16 half8_t __attribute__((ext_vector_type(8)));
typedef float    float4_t __attribute__((ext_vector_type(4)));

// Workspace layout (bytes). Total ~132.2 MB.
#define OFF_VHI   0ull                              // N*DIM fp16 = 128 MB
#define OFF_UHI   (OFF_VHI  + (size_t)N_INST*DIM*2) // DP*DIM fp16 = 2 MB
#define OFF_ULO   (OFF_UHI  + (size_t)DP*DIM*2)     // DP*DIM fp16 = 2 MB
#define OFF_S     (OFF_ULO  + (size_t)DP*DIM*2)     // N fp32 = 128 KB
#define OFF_STAT  (OFF_S    + (size_t)N_INST*4)     // 2 fp32 (padded)
#define OFF_T     (OFF_STAT + 256ull)               // DIM fp32 = 8 KB

#define GLOAD_LDS16(g, l) __builtin_amdgcn_global_load_lds( \
    (__attribute__((address_space(1))) void*)(g),           \
    (__attribute__((address_space(3))) void*)(l), 16, 0, 0)

__device__ __forceinline__ float tanh_fast(float x) {
  // tanh(x) = 1 - 2/(exp(2x)+1); exp overflow->inf gives exact +/-1 limits
  float e = __expf(2.0f * x);
  return 1.0f - 2.0f / (e + 1.0f);
}

// ---- V' fp32 -> fp16 (plain round) ----
__global__ __launch_bounds__(256) void k_conv_v(const float4* __restrict__ in,
                                                half4_t* __restrict__ out) {
  int i = blockIdx.x * 256 + threadIdx.x;
  float4 x = in[i];
  half4_t h;
  h[0] = (_Float16)x.x; h[1] = (_Float16)x.y;
  h[2] = (_Float16)x.z; h[3] = (_Float16)x.w;
  out[i] = h;
}

// ---- U_t fp32 -> fp16 hi + fp16 lo (2-term split) ----
__global__ __launch_bounds__(256) void k_conv_u(const float4* __restrict__ in,
                                                half4_t* __restrict__ hi,
                                                half4_t* __restrict__ lo) {
  int i = blockIdx.x * 256 + threadIdx.x;
  float4 x = in[i];
  float f[4] = {x.x, x.y, x.z, x.w};
  half4_t h, l;
  for (int j = 0; j < 4; ++j) {
    _Float16 a = (_Float16)f[j];
    h[j] = a;
    l[j] = (_Float16)(f[j] - (float)a);
  }
  hi[i] = h;
  lo[i] = l;
}

// ---- fused score GEMM: s[n] = sum_j Wmta[j]*tanh( (Uhi+Ulo)[j,:] . Vhi[n,:] )
// C = U(512xK) @ Vhi(32768xK)^T, 128x128 block tile, BK=32, 4 waves (2x2),
// wave tile 64x64 = 4x4 MFMA 16x16x32 tiles, 2 MFMAs per tile (hi,lo).
__global__ __launch_bounds__(256) void k_score_gemm(
    const _Float16* __restrict__ Uhi, const _Float16* __restrict__ Ulo,
    const _Float16* __restrict__ Vhi, const float* __restrict__ Wmta,
    float* __restrict__ s) {
  __shared__ _Float16 lAh[128 * 32];
  __shared__ _Float16 lAl[128 * 32];
  __shared__ _Float16 lB[128 * 32];

  const int tid = threadIdx.x;
  const int lane = tid & 63;
  const int wv = tid >> 6;        // 0..3
  const int waveM = wv >> 1;      // 0..1
  const int waveN = wv & 1;       // 0..1
  const int quad = lane >> 4;     // 0..3
  const int col = lane & 15;
  // mb fast so the 4 M-blocks sharing a V-tile are temporally adjacent (LLC reuse)
  const int mb = blockIdx.x & 3;   // 512/128
  const int nb = blockIdx.x >> 2;  // 32768/128

  const int aRow0 = mb * 128;
  const int bRow0 = nb * 128;

  float4_t acc[4][4];
  const float4_t z4 = {0.f, 0.f, 0.f, 0.f};
  for (int i = 0; i < 4; i++)
    for (int j = 0; j < 4; j++) acc[i][j] = z4;

  for (int k0 = 0; k0 < DIM; k0 += 32) {
    // stage 3 tiles of 128x32 fp16 (8 KB each) via async global->LDS, 16B/lane
    for (int it = 0; it < 2; ++it) {
      const int slot = it * 256 + tid;
      const int r = slot >> 2;            // row within tile (4 lanes/row)
      const int c = (slot & 3) << 3;      // halves offset within row
      const int lbase = (it * 256 + (wv << 6)) << 3;  // wave-uniform LDS base
      GLOAD_LDS16(Uhi + (size_t)(aRow0 + r) * DIM + k0 + c, &lAh[lbase]);
      GLOAD_LDS16(Ulo + (size_t)(aRow0 + r) * DIM + k0 + c, &lAl[lbase]);
      GLOAD_LDS16(Vhi + (size_t)(bRow0 + r) * DIM + k0 + c, &lB[lbase]);
    }
    __syncthreads();

    half8_t ah[4], al[4], bf[4];
    for (int mi = 0; mi < 4; mi++) {
      const int row = waveM * 64 + mi * 16 + col;
      ah[mi] = *(const half8_t*)&lAh[row * 32 + quad * 8];
      al[mi] = *(const half8_t*)&lAl[row * 32 + quad * 8];
    }
    for (int ni = 0; ni < 4; ni++) {
      const int row = waveN * 64 + ni * 16 + col;
      bf[ni] = *(const half8_t*)&lB[row * 32 + quad * 8];
    }
    for (int mi = 0; mi < 4; mi++)
      for (int ni = 0; ni < 4; ni++) {
        acc[mi][ni] = __builtin_amdgcn_mfma_f32_16x16x32_f16(ah[mi], bf[ni], acc[mi][ni], 0, 0, 0);
        acc[mi][ni] = __builtin_amdgcn_mfma_f32_16x16x32_f16(al[mi], bf[ni], acc[mi][ni], 0, 0, 0);
      }
    __syncthreads();
  }

  // epilogue: C/D layout col=lane&15 (n), row=quad*4+reg (j).
  // reduce over j within block, one atomicAdd per (n, block).
  for (int ni = 0; ni < 4; ni++) {
    float v = 0.0f;
    for (int mi = 0; mi < 4; mi++) {
      const int jb = aRow0 + waveM * 64 + mi * 16 + quad * 4;
      union { float4_t v4; float f[4]; } u;
      u.v4 = acc[mi][ni];
      for (int r = 0; r < 4; r++)
        v += Wmta[jb + r] * tanh_fast(u.f[r]);
    }
    v += __shfl_xor(v, 16);
    v += __shfl_xor(v, 32);
    if (quad == 0) {
      const int n = bRow0 + waveN * 64 + ni * 16 + col;
      atomicAdd(&s[n], v);
    }
  }
}

// ---- softmax stats over s[0..N): max and 1/sum(exp) ----
__global__ __launch_bounds__(1024) void k_stats(const float* __restrict__ s,
                                                float* __restrict__ stats) {
  const int tid = threadIdx.x;
  const int lane = tid & 63;
  const int wv = tid >> 6;
  __shared__ float sm[16];
  __shared__ float bb[2];

  float m = -3.4e38f;
  for (int i = tid; i < N_INST; i += 1024) m = fmaxf(m, s[i]);
  for (int o = 32; o > 0; o >>= 1) m = fmaxf(m, __shfl_xor(m, o));
  if (lane == 0) sm[wv] = m;
  __syncthreads();
  if (tid == 0) {
    float mm = sm[0];
    for (int w = 1; w < 16; w++) mm = fmaxf(mm, sm[w]);
    bb[0] = mm;
  }
  __syncthreads();
  const float mx = bb[0];

  float p = 0.0f;
  for (int i = tid; i < N_INST; i += 1024) p += __expf(s[i] - mx);
  for (int o = 32; o > 0; o >>= 1) p += __shfl_xor(p, o);
  __syncthreads();
  if (lane == 0) sm[wv] = p;
  __syncthreads();
  if (tid == 0) {
    float sum = 0.0f;
    for (int w = 0; w < 16; w++) sum += sm[w];
    stats[0] = mx;
    stats[1] = 1.0f / sum;
  }
}

// ---- pooling: t[d] = sum_n softmax(s)[n] * Vhi[n,d] ----
__global__ __launch_bounds__(256) void k_pool(const _Float16* __restrict__ Vhi,
                                              const float* __restrict__ s,
                                              const float* __restrict__ stats,
                                              float* __restrict__ t) {
  const int tid = threadIdx.x;
  const float mx = stats[0], inv = stats[1];
  const int n0 = blockIdx.x * 64;
  float acc[8] = {0.f, 0.f, 0.f, 0.f, 0.f, 0.f, 0.f, 0.f};
  for (int r = 0; r < 64; ++r) {
    const int n = n0 + r;
    const float w = __expf(s[n] - mx) * inv;
    if (w > 1e-12f) {  // block-uniform branch; skipped terms contribute < 1e-6
      half8_t v = *(const half8_t*)&Vhi[(size_t)n * DIM + tid * 8];
      for (int j = 0; j < 8; ++j) acc[j] += w * (float)v[j];
    }
  }
  for (int j = 0; j < 8; ++j) atomicAdd(&t[tid * 8 + j], acc[j]);
}

// ---- final: l[c] = W[c,:] . t ----
__global__ __launch_bounds__(256) void k_final(const float* __restrict__ W,
                                               const float* __restrict__ t,
                                               float* __restrict__ out) {
  const int wv = threadIdx.x >> 6;  // class id, 4 waves
  const int lane = threadIdx.x & 63;
  float p = 0.0f;
  for (int d = lane; d < DIM; d += 64) p += W[wv * DIM + d] * t[d];
  for (int o = 32; o > 0; o >>= 1) p += __shfl_xor(p, o);
  if (lane == 0) out[wv] = p;
}

extern "C" void kernel_launch(void* const* d_in, const int* in_sizes, int n_in,
                              void* d_out, int out_size, void* d_ws, size_t ws_size,
                              hipStream_t stream) {
  const float* Vp   = (const float*)d_in[0];  // [N, 2048]
  const float* Ut   = (const float*)d_in[1];  // [512, 2048]
  const float* Wmta = (const float*)d_in[2];  // [1, 512]
  const float* W    = (const float*)d_in[3];  // [4, 2048]
  float* out = (float*)d_out;

  char* ws = (char*)d_ws;
  _Float16* Vhi  = (_Float16*)(ws + OFF_VHI);
  _Float16* Uhi  = (_Float16*)(ws + OFF_UHI);
  _Float16* Ulo  = (_Float16*)(ws + OFF_ULO);
  float*    sBuf = (float*)(ws + OFF_S);
  float*    stat = (float*)(ws + OFF_STAT);
  float*    tBuf = (float*)(ws + OFF_T);

  hipMemsetAsync(sBuf, 0, (size_t)N_INST * 4, stream);
  hipMemsetAsync(tBuf, 0, (size_t)DIM * 4, stream);

  k_conv_v<<<(N_INST * (DIM / 4)) / 256, 256, 0, stream>>>((const float4*)Vp, (half4_t*)Vhi);
  k_conv_u<<<(DP * (DIM / 4)) / 256, 256, 0, stream>>>((const float4*)Ut, (half4_t*)Uhi, (half4_t*)Ulo);
  k_score_gemm<<<(DP / 128) * (N_INST / 128), 256, 0, stream>>>(Uhi, Ulo, Vhi, Wmta, sBuf);
  k_stats<<<1, 1024, 0, stream>>>(sBuf, stat);
  k_pool<<<N_INST / 64, 256, 0, stream>>>(Vhi, sBuf, stat, tBuf);
  k_final<<<1, 256, 0, stream>>>(W, tBuf, out);
}

// Round 2
// 540.911 us; speedup vs baseline: 1.2165x; 1.2165x over previous
//
#include <hip/hip_runtime.h>

// Problem constants (fixed shapes from reference setup_inputs)
#define N_INST 32768
#define DIM    2048
#define DP     512
#define NCLS   4

typedef _Float16 half4_t __attribute__((ext_vector_type(4)));
typedef _Float16 half8_t __attribute__((ext_vector_type(8)));
typedef float    float4_t __attribute__((ext_vector_type(4)));

// Workspace layout (bytes). Total ~132.1 MB.
#define OFF_VHI   0ull                              // N*DIM fp16 = 128 MB
#define OFF_UHI   (OFF_VHI  + (size_t)N_INST*DIM*2) // DP*DIM fp16 = 2 MB
#define OFF_S     (OFF_UHI  + (size_t)DP*DIM*2)     // N fp32 = 128 KB
#define OFF_STAT  (OFF_S    + (size_t)N_INST*4)     // 2 fp32 (padded)
#define OFF_PART  (OFF_STAT + 256ull)               // 256*DIM fp32 = 2 MB
#define OFF_T     (OFF_PART + 256ull*DIM*4)         // DIM fp32 = 8 KB

#define GLOAD_LDS16(g, l) __builtin_amdgcn_global_load_lds( \
    (__attribute__((address_space(1))) void*)(g),           \
    (__attribute__((address_space(3))) void*)(l), 16, 0, 0)

__device__ __forceinline__ float tanh_fast(float x) {
  // tanh(x) = 1 - 2/(exp(2x)+1); exp overflow->inf gives exact +/-1 limits
  float e = __expf(2.0f * x);
  return 1.0f - 2.0f / (e + 1.0f);
}

// ---- fp32 -> fp16 convert, 8 elems/thread (32B load, 16B store) ----
__global__ __launch_bounds__(256) void k_cvt(const float4* __restrict__ in,
                                             half8_t* __restrict__ out) {
  int i = blockIdx.x * 256 + threadIdx.x;
  float4 a = in[2 * i], b = in[2 * i + 1];
  half8_t h;
  h[0] = (_Float16)a.x; h[1] = (_Float16)a.y;
  h[2] = (_Float16)a.z; h[3] = (_Float16)a.w;
  h[4] = (_Float16)b.x; h[5] = (_Float16)b.y;
  h[6] = (_Float16)b.z; h[7] = (_Float16)b.w;
  out[i] = h;
}

// ---- fused score GEMM: s[n] = sum_j Wmta[j]*tanh( Uhi[j,:] . Vhi[n,:] )
// C = U(512xK) @ Vhi(32768xK)^T, 128x128 block tile, BK=32, 4 waves (2x2),
// wave tile 64x64 = 4x4 MFMA 16x16x32 tiles.
__global__ __launch_bounds__(256) void k_score_gemm(
    const _Float16* __restrict__ Uhi, const _Float16* __restrict__ Vhi,
    const float* __restrict__ Wmta, float* __restrict__ s) {
  __shared__ _Float16 lA[128 * 32];
  __shared__ _Float16 lB[128 * 32];

  const int tid = threadIdx.x;
  const int lane = tid & 63;
  const int wv = tid >> 6;        // 0..3
  const int waveM = wv >> 1;      // 0..1
  const int waveN = wv & 1;       // 0..1
  const int quad = lane >> 4;     // 0..3
  const int col = lane & 15;
  // mb fast so the 4 M-blocks sharing a V-tile are temporally adjacent (L2/LLC reuse)
  const int mb = blockIdx.x & 3;   // 512/128
  const int nb = blockIdx.x >> 2;  // 32768/128

  const int aRow0 = mb * 128;
  const int bRow0 = nb * 128;

  float4_t acc[4][4];
  const float4_t z4 = {0.f, 0.f, 0.f, 0.f};
  for (int i = 0; i < 4; i++)
    for (int j = 0; j < 4; j++) acc[i][j] = z4;

  for (int k0 = 0; k0 < DIM; k0 += 32) {
    // stage 2 tiles of 128x32 fp16 (8 KB each) via async global->LDS, 16B/lane
    for (int it = 0; it < 2; ++it) {
      const int slot = it * 256 + tid;
      const int r = slot >> 2;            // row within tile (4 lanes/row)
      const int c = (slot & 3) << 3;      // halves offset within row
      const int lbase = (it * 256 + (wv << 6)) << 3;  // wave-uniform LDS base (halves)
      GLOAD_LDS16(Uhi + (size_t)(aRow0 + r) * DIM + k0 + c, &lA[lbase]);
      GLOAD_LDS16(Vhi + (size_t)(bRow0 + r) * DIM + k0 + c, &lB[lbase]);
    }
    __syncthreads();

    half8_t af[4], bf[4];
    for (int mi = 0; mi < 4; mi++) {
      const int row = waveM * 64 + mi * 16 + col;
      af[mi] = *(const half8_t*)&lA[row * 32 + quad * 8];
    }
    for (int ni = 0; ni < 4; ni++) {
      const int row = waveN * 64 + ni * 16 + col;
      bf[ni] = *(const half8_t*)&lB[row * 32 + quad * 8];
    }
    for (int mi = 0; mi < 4; mi++)
      for (int ni = 0; ni < 4; ni++)
        acc[mi][ni] = __builtin_amdgcn_mfma_f32_16x16x32_f16(af[mi], bf[ni], acc[mi][ni], 0, 0, 0);
    __syncthreads();
  }

  // epilogue: C/D layout col=lane&15 (n), row=quad*4+reg (j).
  // reduce over j within block, one atomicAdd per (n, block). 8 adders/address.
  for (int ni = 0; ni < 4; ni++) {
    float v = 0.0f;
    for (int mi = 0; mi < 4; mi++) {
      const int jb = aRow0 + waveM * 64 + mi * 16 + quad * 4;
      union { float4_t v4; float f[4]; } u;
      u.v4 = acc[mi][ni];
      for (int r = 0; r < 4; r++)
        v += Wmta[jb + r] * tanh_fast(u.f[r]);
    }
    v += __shfl_xor(v, 16);
    v += __shfl_xor(v, 32);
    if (quad == 0) {
      const int n = bRow0 + waveN * 64 + ni * 16 + col;
      atomicAdd(&s[n], v);
    }
  }
}

// ---- softmax stats over s[0..N): max and 1/sum(exp) ----
__global__ __launch_bounds__(1024) void k_stats(const float* __restrict__ s,
                                                float* __restrict__ stats) {
  const int tid = threadIdx.x;
  const int lane = tid & 63;
  const int wv = tid >> 6;
  __shared__ float sm[16];
  __shared__ float bb;
  const float4* s4 = (const float4*)s;

  float m = -3.4e38f;
  for (int i = tid; i < N_INST / 4; i += 1024) {
    float4 v = s4[i];
    m = fmaxf(m, fmaxf(fmaxf(v.x, v.y), fmaxf(v.z, v.w)));
  }
  for (int o = 32; o > 0; o >>= 1) m = fmaxf(m, __shfl_xor(m, o));
  if (lane == 0) sm[wv] = m;
  __syncthreads();
  if (tid == 0) {
    float mm = sm[0];
    for (int w = 1; w < 16; w++) mm = fmaxf(mm, sm[w]);
    bb = mm;
  }
  __syncthreads();
  const float mx = bb;

  float p = 0.0f;
  for (int i = tid; i < N_INST / 4; i += 1024) {
    float4 v = s4[i];
    p += __expf(v.x - mx) + __expf(v.y - mx) + __expf(v.z - mx) + __expf(v.w - mx);
  }
  for (int o = 32; o > 0; o >>= 1) p += __shfl_xor(p, o);
  if (lane == 0) sm[wv] = p;
  __syncthreads();
  if (tid == 0) {
    float sum = 0.0f;
    for (int w = 0; w < 16; w++) sum += sm[w];
    stats[0] = mx;
    stats[1] = 1.0f / sum;
  }
}

// ---- pooling partials: part[b][d] = sum_{n in block b} w[n] * Vhi[n,d]
// No atomics: each block owns its partial row.
__global__ __launch_bounds__(256) void k_pool(const _Float16* __restrict__ Vhi,
                                              const float* __restrict__ s,
                                              const float* __restrict__ stats,
                                              float* __restrict__ part) {
  const int tid = threadIdx.x;
  const float mx = stats[0], inv = stats[1];
  const int n0 = blockIdx.x * 128;
  float acc[8] = {0.f, 0.f, 0.f, 0.f, 0.f, 0.f, 0.f, 0.f};
  for (int r = 0; r < 128; ++r) {
    const int n = n0 + r;
    const float w = __expf(s[n] - mx) * inv;
    if (w > 1e-12f) {  // block-uniform branch; skipped terms contribute < 1e-6
      half8_t v = *(const half8_t*)&Vhi[(size_t)n * DIM + tid * 8];
#pragma unroll
      for (int j = 0; j < 8; ++j) acc[j] += w * (float)v[j];
    }
  }
  float* dst = &part[(size_t)blockIdx.x * DIM + tid * 8];
  *(float4*)(dst + 0) = make_float4(acc[0], acc[1], acc[2], acc[3]);
  *(float4*)(dst + 4) = make_float4(acc[4], acc[5], acc[6], acc[7]);
}

// ---- reduce partials: t[d] = sum_b part[b][d]; 2 MB, L2-resident ----
__global__ __launch_bounds__(256) void k_reduce(const float* __restrict__ part,
                                                float* __restrict__ t) {
  const int d = blockIdx.x * 256 + threadIdx.x;
  float acc = 0.f;
  for (int b = 0; b < 256; ++b) acc += part[(size_t)b * DIM + d];
  t[d] = acc;
}

// ---- final: l[c] = W[c,:] . t ----
__global__ __launch_bounds__(256) void k_final(const float* __restrict__ W,
                                               const float* __restrict__ t,
                                               float* __restrict__ out) {
  const int wv = threadIdx.x >> 6;  // class id, 4 waves
  const int lane = threadIdx.x & 63;
  float p = 0.0f;
  for (int d = lane; d < DIM; d += 64) p += W[wv * DIM + d] * t[d];
  for (int o = 32; o > 0; o >>= 1) p += __shfl_xor(p, o);
  if (lane == 0) out[wv] = p;
}

extern "C" void kernel_launch(void* const* d_in, const int* in_sizes, int n_in,
                              void* d_out, int out_size, void* d_ws, size_t ws_size,
                              hipStream_t stream) {
  const float* Vp   = (const float*)d_in[0];  // [N, 2048]
  const float* Ut   = (const float*)d_in[1];  // [512, 2048]
  const float* Wmta = (const float*)d_in[2];  // [1, 512]
  const float* W    = (const float*)d_in[3];  // [4, 2048]
  float* out = (float*)d_out;

  char* ws = (char*)d_ws;
  _Float16* Vhi  = (_Float16*)(ws + OFF_VHI);
  _Float16* Uhi  = (_Float16*)(ws + OFF_UHI);
  float*    sBuf = (float*)(ws + OFF_S);
  float*    stat = (float*)(ws + OFF_STAT);
  float*    partB= (float*)(ws + OFF_PART);
  float*    tBuf = (float*)(ws + OFF_T);

  hipMemsetAsync(sBuf, 0, (size_t)N_INST * 4, stream);

  k_cvt<<<(N_INST * DIM / 8) / 256, 256, 0, stream>>>((const float4*)Vp, (half8_t*)Vhi);
  k_cvt<<<(DP * DIM / 8) / 256, 256, 0, stream>>>((const float4*)Ut, (half8_t*)Uhi);
  k_score_gemm<<<(DP / 128) * (N_INST / 128), 256, 0, stream>>>(Uhi, Vhi, Wmta, sBuf);
  k_stats<<<1, 1024, 0, stream>>>(sBuf, stat);
  k_pool<<<N_INST / 128, 256, 0, stream>>>(Vhi, sBuf, stat, partB);
  k_reduce<<<DIM / 256, 256, 0, stream>>>(partB, tBuf);
  k_final<<<1, 256, 0, stream>>>(W, tBuf, out);
}